// Round 4
// baseline (1509.634 us; speedup 1.0000x reference)
//
#include <hip/hip_runtime.h>
#include <hip/hip_bf16.h>
#include <math.h>

#define BATCH   1024
#define SEQ     80
#define EMB     512
#define UNITS   512
#define NBG     32           // batch groups (32 rows each)
#define NCG     8            // col groups (64 cols each)
#define ROWS    32
#define COLS    64
#define THREADS 256          // 4 waves; wave w owns cols [cg*64 + w*16, +16)

#define H0_OFF   (2u * 1024 * 1024)
#define H1_OFF   (4u * 1024 * 1024)
#define FLAG_OFF (6u * 1024 * 1024)

typedef __attribute__((ext_vector_type(8))) short          bf16x8;
typedef __attribute__((ext_vector_type(8))) unsigned short u16x8;
typedef __attribute__((ext_vector_type(4))) float          f32x4;

__device__ inline unsigned short f2bf(float f) {
    __hip_bfloat16 h = __float2bfloat16(f);
    return *reinterpret_cast<unsigned short*>(&h);
}
__device__ inline float bf2f(unsigned short u) {
    unsigned int x = ((unsigned int)u) << 16;
    return __uint_as_float(x);
}
__device__ inline float tanh_fast(float x) {
    float e = __expf(2.f * x);
    return 1.f - 2.f / (e + 1.f);
}

// ---------------------------------------------------------------------------
// Pack weights into per-(phase, cg, wave, k0) B-fragment slabs, bf16.
// g = ((p*8 + cg)*4 + w)*32 + k0 ; elem = g*512 + lane*8 + j
// value = Wp[k0*32 + (lane>>4)*8 + j][cg*64 + w*16 + (lane&15)]
// Wp rows: [Wx ; Wh] stacked (K=1024).
// ---------------------------------------------------------------------------
__global__ __launch_bounds__(256) void pack_weights(
    const float* __restrict__ W0x, const float* __restrict__ W0h,
    const float* __restrict__ W1x, const float* __restrict__ W1h,
    unsigned short* __restrict__ wpack)
{
    int g    = blockIdx.x * 4 + (threadIdx.x >> 6);   // 0..2047
    int lane = threadIdx.x & 63;
    int p    = g >> 10;
    int cg   = (g >> 7) & 7;
    int w    = (g >> 5) & 3;
    int k0   = g & 31;
    int n    = cg * COLS + w * 16 + (lane & 15);
    int kb   = k0 * 32 + (lane >> 4) * 8;
    const float* Wx = p ? W1x : W0x;
    const float* Wh = p ? W1h : W0h;

    u16x8 v;
#pragma unroll
    for (int j = 0; j < 8; ++j) {
        int k = kb + j;
        float f = (k < 512) ? Wx[(size_t)k * UNITS + n]
                            : Wh[(size_t)(k - 512) * UNITS + n];
        v[j] = f2bf(f);
    }
    *(u16x8*)(wpack + (size_t)g * 512 + lane * 8) = v;
}

// K-loop: NK iters, two 16-row A tiles, depth-8 B prefetch.
// hcat granule (16B) index = GBASE + i*4 + quad, XOR-swizzled by (l15&7).
template<int NK, int GBASE>
__device__ __forceinline__ void run_k(
    f32x4& acc0, f32x4& acc1,
    const unsigned short* __restrict__ wb,    // + lane*8 pre-added, at first k0 slab
    const unsigned short* hcat, int l15, int quad, int sw)
{
    bf16x8 Bf[8];
    constexpr int PRE = (NK < 8) ? NK : 8;
#pragma unroll
    for (int i = 0; i < PRE; ++i)
        Bf[i] = *(const bf16x8*)(wb + (size_t)i * 512);
#pragma unroll
    for (int i = 0; i < NK; ++i) {
        int g0 = ((GBASE + i * 4 + quad) ^ sw) * 8;
        bf16x8 a0 = *(const bf16x8*)(hcat + l15 * 1024 + g0);
        bf16x8 a1 = *(const bf16x8*)(hcat + (16 + l15) * 1024 + g0);
        bf16x8 b  = Bf[i & 7];
        if (i + 8 < NK)
            Bf[i & 7] = *(const bf16x8*)(wb + (size_t)(i + 8) * 512);
        acc0 = __builtin_amdgcn_mfma_f32_16x16x32_bf16(a0, b, acc0, 0, 0, 0);
        acc1 = __builtin_amdgcn_mfma_f32_16x16x32_bf16(a1, b, acc1, 0, 0, 0);
    }
}

// ---------------------------------------------------------------------------
// 256 blocks = 32 bg x 8 cg, 1/CU. Per block: 32 rows x 64 cols.
// LDS 64 KB: per row 1024 ushorts = S0 (granules 0..63: x / h1 time-shared)
//                                 | S1 (granules 64..127: h0).
// Pipelined step: publish h0 -> B1/flag -> [emb prefetch + phase2a(h1)] ->
// spin/B2 -> gather h0 + stage x -> B3 -> phase2b(h0) -> publish h1 -> B4/flag
// -> phase1(t+1) full -> spin/B5 -> gather h1.
// ---------------------------------------------------------------------------
__global__ __launch_bounds__(THREADS, 1) void rnn_ex_kernel(
    const int*   __restrict__ inputs,
    const float* __restrict__ emb,
    const float* __restrict__ b0,
    const float* __restrict__ b1,
    const unsigned short* __restrict__ wpack,
    unsigned short* __restrict__ h0buf,   // [2][1024][512] bf16
    unsigned short* __restrict__ h1buf,   // [2][1024][512] bf16
    int* __restrict__ flag0,              // [32][8]
    int* __restrict__ flag1,              // [32][8]
    const float* __restrict__ Wout,
    const float* __restrict__ bout,
    float*       __restrict__ out)
{
    __shared__ unsigned short hcat[ROWS * 1024];   // 65536 B

    const int tid   = threadIdx.x;
    const int w     = tid >> 6;
    const int lane  = tid & 63;
    const int quad  = lane >> 4;
    const int l15   = lane & 15;
    const int sw    = l15 & 7;
    const int cg    = blockIdx.x >> 5;    // 0..7
    const int bg    = blockIdx.x & 31;    // 0..31
    const int rbase = bg * ROWS;

    // zero S1 (h0 region)
    for (int i = tid; i < ROWS * 512; i += THREADS) {
        int r = i >> 9, c = i & 511;
        hcat[r * 1024 + 512 + c] = 0;
    }

    const int xrow = tid >> 3;        // 0..31
    const int xl8  = tid & 7;

    // stage x_0 into S0
    {
        int idx = inputs[(rbase + xrow) * SEQ + 0];
        const float* ep = emb + (size_t)idx * EMB;
#pragma unroll
        for (int i = 0; i < 8; ++i) {
            int c8 = i * 8 + xl8;
            float4 fa = *(const float4*)(ep + c8 * 8);
            float4 fb = *(const float4*)(ep + c8 * 8 + 4);
            u16x8 v;
            v[0]=f2bf(fa.x); v[1]=f2bf(fa.y); v[2]=f2bf(fa.z); v[3]=f2bf(fa.w);
            v[4]=f2bf(fb.x); v[5]=f2bf(fb.y); v[6]=f2bf(fb.z); v[7]=f2bf(fb.w);
            *(u16x8*)(hcat + xrow * 1024 + ((c8 ^ (xrow & 7)) * 8)) = v;
        }
    }
    __syncthreads();

    const int   mycol = cg * COLS + w * 16 + l15;
    const float bias0 = b0[mycol];
    const float bias1 = b1[mycol];

    const unsigned short* wb0 = wpack + ((size_t)(cg * 4 + w) * 32) * 512 + lane * 8;
    const unsigned short* wb1 = wb0 + (size_t)1024 * 512;
    const int fl = bg * NCG;

    // preamble: phase1(0) over [x(0) | h0=0]
    f32x4 acc0  = {bias0, bias0, bias0, bias0};
    f32x4 acc0b = acc0;
    run_k<32, 0>(acc0, acc0b, wb0, hcat, l15, quad, sw);

    for (int t = 0; t < SEQ; ++t) {
        const int par = t & 1;
        const int tgt = t + 1;

        // publish h0(t) = tanh(acc0) slices (agent relaxed, write-through)
        {
            unsigned short* dst = h0buf +
                ((size_t)par * BATCH + rbase + quad * 4) * UNITS + mycol;
#pragma unroll
            for (int i = 0; i < 4; ++i) {
                __hip_atomic_store(dst + (size_t)i * UNITS,
                    f2bf(tanh_fast(acc0[i])), __ATOMIC_RELAXED, __HIP_MEMORY_SCOPE_AGENT);
                __hip_atomic_store(dst + (size_t)(16 + i) * UNITS,
                    f2bf(tanh_fast(acc0b[i])), __ATOMIC_RELAXED, __HIP_MEMORY_SCOPE_AGENT);
            }
        }
        int tn  = (t + 1 < SEQ) ? t + 1 : t;
        int idx = inputs[(rbase + xrow) * SEQ + tn];    // drains at B1
        __syncthreads();                                               // B1
        if (tid == 0)
            __hip_atomic_store(&flag0[fl + cg], tgt,
                               __ATOMIC_RELEASE, __HIP_MEMORY_SCOPE_AGENT);

        // emb prefetch for x(t+1), in flight across phase2a
        const float* ep = emb + (size_t)idx * EMB;
        float4 xf[16];
#pragma unroll
        for (int i = 0; i < 8; ++i) {
            int c8 = i * 8 + xl8;
            xf[2 * i]     = *(const float4*)(ep + c8 * 8);
            xf[2 * i + 1] = *(const float4*)(ep + c8 * 8 + 4);
        }

        // phase2a: h1(t-1) half (S0), W1h slabs (k0 16..31)
        f32x4 acc2  = {bias1, bias1, bias1, bias1};
        f32x4 acc2b = acc2;
        if (t > 0)
            run_k<16, 0>(acc2, acc2b, wb1 + (size_t)16 * 512, hcat, l15, quad, sw);

        if (tid < NCG)
            while (__hip_atomic_load(&flag0[fl + tid],
                                     __ATOMIC_RELAXED, __HIP_MEMORY_SCOPE_AGENT) < tgt)
                __builtin_amdgcn_s_sleep(1);
        __asm__ volatile("" ::: "memory");
        __syncthreads();                                               // B2

        // gather h0(t) -> S1 ; stage x(t+1) -> S0
        {
            const unsigned long long* src = (const unsigned long long*)
                (h0buf + ((size_t)par * BATCH + rbase) * UNITS);
#pragma unroll
            for (int j = 0; j < 8; ++j) {
                int G = j * 256 + tid;
                int r = G >> 6, c8 = G & 63;
                unsigned long long q0 = __hip_atomic_load(src + (size_t)G * 2,
                    __ATOMIC_RELAXED, __HIP_MEMORY_SCOPE_AGENT);
                unsigned long long q1 = __hip_atomic_load(src + (size_t)G * 2 + 1,
                    __ATOMIC_RELAXED, __HIP_MEMORY_SCOPE_AGENT);
                int off = r * 1024 + ((64 + c8) ^ (r & 7)) * 8;
                *(unsigned long long*)(hcat + off)     = q0;
                *(unsigned long long*)(hcat + off + 4) = q1;
            }
#pragma unroll
            for (int i = 0; i < 8; ++i) {
                int c8 = i * 8 + xl8;
                float4 fa = xf[2 * i], fb = xf[2 * i + 1];
                u16x8 v;
                v[0]=f2bf(fa.x); v[1]=f2bf(fa.y); v[2]=f2bf(fa.z); v[3]=f2bf(fa.w);
                v[4]=f2bf(fb.x); v[5]=f2bf(fb.y); v[6]=f2bf(fb.z); v[7]=f2bf(fb.w);
                *(u16x8*)(hcat + xrow * 1024 + ((c8 ^ (xrow & 7)) * 8)) = v;
            }
        }
        __syncthreads();                                               // B3

        // phase2b: h0(t) half (S1), W1x slabs (k0 0..15)
        run_k<16, 64>(acc2, acc2b, wb1, hcat, l15, quad, sw);

        // publish h1(t)
        {
            unsigned short* dst = h1buf +
                ((size_t)par * BATCH + rbase + quad * 4) * UNITS + mycol;
#pragma unroll
            for (int i = 0; i < 4; ++i) {
                __hip_atomic_store(dst + (size_t)i * UNITS,
                    f2bf(tanh_fast(acc2[i])), __ATOMIC_RELAXED, __HIP_MEMORY_SCOPE_AGENT);
                __hip_atomic_store(dst + (size_t)(16 + i) * UNITS,
                    f2bf(tanh_fast(acc2b[i])), __ATOMIC_RELAXED, __HIP_MEMORY_SCOPE_AGENT);
            }
        }
        __syncthreads();                                               // B4
        if (tid == 0)
            __hip_atomic_store(&flag1[fl + cg], tgt,
                               __ATOMIC_RELEASE, __HIP_MEMORY_SCOPE_AGENT);

        // phase1(t+1) over [x(t+1) | h0(t)] — hides the h1 exchange
        acc0 = (f32x4){bias0, bias0, bias0, bias0};
        acc0b = acc0;
        if (t + 1 < SEQ)
            run_k<32, 0>(acc0, acc0b, wb0, hcat, l15, quad, sw);

        if (tid < NCG)
            while (__hip_atomic_load(&flag1[fl + tid],
                                     __ATOMIC_RELAXED, __HIP_MEMORY_SCOPE_AGENT) < tgt)
                __builtin_amdgcn_s_sleep(1);
        __asm__ volatile("" ::: "memory");
        __syncthreads();                                               // B5

        // gather h1(t) -> S0 (x(t+1) already consumed by phase1(t+1))
        {
            const unsigned long long* src = (const unsigned long long*)
                (h1buf + ((size_t)par * BATCH + rbase) * UNITS);
#pragma unroll
            for (int j = 0; j < 8; ++j) {
                int G = j * 256 + tid;
                int r = G >> 6, c8 = G & 63;
                unsigned long long q0 = __hip_atomic_load(src + (size_t)G * 2,
                    __ATOMIC_RELAXED, __HIP_MEMORY_SCOPE_AGENT);
                unsigned long long q1 = __hip_atomic_load(src + (size_t)G * 2 + 1,
                    __ATOMIC_RELAXED, __HIP_MEMORY_SCOPE_AGENT);
                int off = r * 1024 + ((c8 ^ (r & 7)) * 8);
                *(unsigned long long*)(hcat + off)     = q0;
                *(unsigned long long*)(hcat + off + 4) = q1;
            }
        }
        // next-step B1 orders these writes before phase2a(t+1) reads
    }
    __syncthreads();

    // epilogue: out = sigmoid(h1(79) @ Wout + bout); cg==0 blocks, 8 rows/wave
    if (cg == 0) {
#pragma unroll
        for (int rr = 0; rr < 8; ++rr) {
            int r = w * 8 + rr;
            float s = 0.f;
#pragma unroll
            for (int j = 0; j < 8; ++j) {
                int c  = lane + 64 * j;
                int c8 = c >> 3, ci = c & 7;
                s += bf2f(hcat[r * 1024 + ((c8 ^ (r & 7)) * 8) + ci]) * Wout[c];
            }
#pragma unroll
            for (int off = 32; off > 0; off >>= 1) s += __shfl_down(s, off);
            if (lane == 0) {
                float z = s + bout[0];
                out[rbase + r] = 1.f / (1.f + __expf(-z));
            }
        }
    }
}

extern "C" void kernel_launch(void* const* d_in, const int* in_sizes, int n_in,
                              void* d_out, int out_size, void* d_ws, size_t ws_size,
                              hipStream_t stream) {
    const int*   inputs = (const int*)d_in[0];
    const float* emb    = (const float*)d_in[1];
    const float* W0x    = (const float*)d_in[2];
    const float* W0h    = (const float*)d_in[3];
    const float* b0     = (const float*)d_in[4];
    const float* W1x    = (const float*)d_in[5];
    const float* W1h    = (const float*)d_in[6];
    const float* b1     = (const float*)d_in[7];
    const float* Wout   = (const float*)d_in[8];
    const float* bout   = (const float*)d_in[9];
    float*       out    = (float*)d_out;

    unsigned short* wpack = (unsigned short*)d_ws;                      // 2 MB
    unsigned short* h0buf = (unsigned short*)((char*)d_ws + H0_OFF);    // 2 MB
    unsigned short* h1buf = (unsigned short*)((char*)d_ws + H1_OFF);    // 2 MB
    int* flag0 = (int*)((char*)d_ws + FLAG_OFF);                        // 1 KB
    int* flag1 = flag0 + 256;                                           // 1 KB

    hipMemsetAsync((char*)d_ws + FLAG_OFF, 0, 2048, stream);
    pack_weights<<<512, 256, 0, stream>>>(W0x, W0h, W1x, W1h, wpack);
    rnn_ex_kernel<<<NBG * NCG, THREADS, 0, stream>>>(
        inputs, emb, b0, b1, wpack, h0buf, h1buf, flag0, flag1,
        Wout, bout, out);
}